// Round 8
// baseline (244.171 us; speedup 1.0000x reference)
//
#include <hip/hip_runtime.h>
#include <hip/hip_bf16.h>

// B=1 T=64 W=88 HP=48 F0=53 HL=12 GATES=48 NU=24 NH=4 HD=6 K=25
// All float tensors are float32; condition is int32.
#define NPIX (64*88)          // 5632
#define NSEQ 88
#define TT 64
#define F0 53
#define GATES 48

typedef __hip_bfloat16 bf16;

__device__ __forceinline__ float sigm(float x){ return 1.0f/(1.0f+__expf(-x)); }
__device__ __forceinline__ float tanhfast(float x){ return 2.0f/(1.0f+__expf(-2.0f*x)) - 1.0f; }
__device__ __forceinline__ float rl(float v, int l){
  return __uint_as_float(__builtin_amdgcn_readlane(__float_as_uint(v), l));
}
__device__ __forceinline__ float blo(unsigned u){ return __uint_as_float(u<<16); }
__device__ __forceinline__ float bhi(unsigned u){ return __uint_as_float(u & 0xffff0000u); }

// ============ D1: build x-tile + gates layer 0, whole-GPU parallel =========
__global__ __launch_bounds__(256) void k_gates0(
    const float* __restrict__ feat, const int* __restrict__ cond,
    const float* __restrict__ mask, const float* __restrict__ emb,
    const float* __restrict__ wih0, const float* __restrict__ bih0,
    const float* __restrict__ bhh0, float* __restrict__ gp){
  int n = blockIdx.x >> 3; int tc = blockIdx.x & 7; int t0 = tc*8;
  int tid = threadIdx.x;
  __shared__ float sx[8*F0];
  __shared__ float sw[2*GATES*F0];  // stride 53 (coprime with 32 banks)

  for (int idx = tid; idx < 2*GATES*F0; idx += 256) sw[idx] = wih0[idx];
  for (int idx = tid; idx < 8*F0; idx += 256){
    int tl = idx / F0, f = idx - tl*F0; int t = t0 + tl;
    float v;
    if (f < 48)      v = feat[(t*48 + f)*88 + n];
    else if (f < 52) v = emb[cond[t*88+n]*4 + (f-48)];
    else             v = mask[t*88+n];
    sx[idx] = v;
  }
  __syncthreads();

  #pragma unroll
  for (int r = 0; r < 3; ++r){
    int row = tid + r*256;
    int d = row / 384; int rem = row - d*384;
    int tl = rem / 48; int j = rem - tl*48;
    const float* xr = sx + tl*F0;
    const float* wr = sw + (d*GATES + j)*F0;
    float a0=0.f, a1=0.f, a2=0.f, a3=0.f;
    #pragma unroll
    for (int f=0; f<52; f+=4){
      a0 += xr[f  ]*wr[f  ];
      a1 += xr[f+1]*wr[f+1];
      a2 += xr[f+2]*wr[f+2];
      a3 += xr[f+3]*wr[f+3];
    }
    float acc = bih0[d*GATES+j] + bhh0[d*GATES+j] + xr[52]*wr[52]
              + ((a0+a1)+(a2+a3));
    gp[((d*NSEQ + n)*TT + (t0+tl))*GATES + j] = acc;
  }
}

// ============ D2: serial core — rec0, gates1, rec1, qkv. 88 blocks ========
// Recurrence: lane j owns h_j; each lane computes all 4 of its gates.
// h broadcast via v_readlane (SGPR), no ds_bpermute in the serial chain.
__global__ __launch_bounds__(256) void k_core(
    const float* __restrict__ gp, const float* __restrict__ whh0,
    const float* __restrict__ wih1, const float* __restrict__ bih1,
    const float* __restrict__ bhh1, const float* __restrict__ whh1,
    const float* __restrict__ qkv_w, const float* __restrict__ qkv_b,
    float* __restrict__ q, bf16* __restrict__ kvh){
  int n = blockIdx.x; int tid = threadIdx.x;
  int wave = tid >> 6; int lane = tid & 63;
  __shared__ float y0[TT*24];
  __shared__ float y1[TT*24];
  __shared__ float gbuf[2*TT*GATES];  // staged gp tile, later reused as g1
  __shared__ float w1[2*GATES*25];    // wih1 padded stride 25
  __shared__ float sqkv[72*25];       // qkv_w padded stride 25

  // ---- stage: gate tile (24 KB), wih1, qkv_w ----
  {
    const float4* src0 = (const float4*)(gp + (size_t)(0*NSEQ + n)*TT*GATES);
    const float4* src1 = (const float4*)(gp + (size_t)(1*NSEQ + n)*TT*GATES);
    float4* dst = (float4*)gbuf;
    for (int idx = tid; idx < TT*GATES/4; idx += 256){
      dst[idx] = src0[idx];
      dst[idx + TT*GATES/4] = src1[idx];
    }
  }
  for (int idx = tid; idx < 2*GATES*24; idx += 256){
    int row = idx / 24, f = idx - row*24;
    w1[row*25 + f] = wih1[idx];
  }
  for (int idx = tid; idx < 72*24; idx += 256){
    int row = idx / 24, f = idx - row*24;
    sqkv[row*25 + f] = qkv_w[idx];
  }
  __syncthreads();

  // ---- recurrence layer 0: wave d in {0,1} -------------------------------
  if (wave < 2){
    int d = wave;
    int j = lane % 12;
    float wi[12], wf[12], wg[12], wo[12];
    const float* wb = whh0 + d*GATES*12;
    #pragma unroll
    for (int m=0;m<12;++m){
      wi[m] = wb[(j   )*12+m];
      wf[m] = wb[(j+12)*12+m];
      wg[m] = wb[(j+24)*12+m];
      wo[m] = wb[(j+36)*12+m];
    }
    const float* gbase = gbuf + d*TT*GATES;
    float hval = 0.f, cval = 0.f;
    for (int s=0;s<TT;++s){
      int t = d ? (TT-1-s) : s;
      const float* gr = gbase + t*GATES;
      float gi = gr[j], gf = gr[j+12], gg = gr[j+24], go = gr[j+36];
      #pragma unroll
      for (int m=0;m<12;++m){
        float hm = rl(hval, m);
        gi += hm*wi[m]; gf += hm*wf[m]; gg += hm*wg[m]; go += hm*wo[m];
      }
      float cn = sigm(gf)*cval + sigm(gi)*tanhfast(gg);
      float hn = sigm(go)*tanhfast(cn);
      cval = cn; hval = hn;
      if (lane < 12) y0[t*24 + d*12 + lane] = hn;
    }
  }
  __syncthreads();

  // ---- gates layer 1 (overwrites gbuf) -----------------------------------
  #pragma unroll
  for (int r = 0; r < 24; ++r){
    int row = tid + r*256;
    int d = row / 3072; int rem = row - d*3072;
    int t = rem / 48; int j = rem - t*48;
    const float* xr = y0 + t*24;
    const float* wr = w1 + (d*GATES + j)*25;
    float a0=0.f, a1=0.f;
    #pragma unroll
    for (int c=0; c<24; c+=2){ a0 += xr[c]*wr[c]; a1 += xr[c+1]*wr[c+1]; }
    gbuf[(d*TT + t)*GATES + j] = bih1[d*GATES+j] + bhh1[d*GATES+j] + a0 + a1;
  }
  __syncthreads();

  // ---- recurrence layer 1 ------------------------------------------------
  if (wave < 2){
    int d = wave;
    int j = lane % 12;
    float wi[12], wf[12], wg[12], wo[12];
    const float* wb = whh1 + d*GATES*12;
    #pragma unroll
    for (int m=0;m<12;++m){
      wi[m] = wb[(j   )*12+m];
      wf[m] = wb[(j+12)*12+m];
      wg[m] = wb[(j+24)*12+m];
      wo[m] = wb[(j+36)*12+m];
    }
    const float* gbase = gbuf + d*TT*GATES;
    float hval = 0.f, cval = 0.f;
    for (int s=0;s<TT;++s){
      int t = d ? (TT-1-s) : s;
      const float* gr = gbase + t*GATES;
      float gi = gr[j], gf = gr[j+12], gg = gr[j+24], go = gr[j+36];
      #pragma unroll
      for (int m=0;m<12;++m){
        float hm = rl(hval, m);
        gi += hm*wi[m]; gf += hm*wf[m]; gg += hm*wg[m]; go += hm*wo[m];
      }
      float cn = sigm(gf)*cval + sigm(gi)*tanhfast(gg);
      float hn = sigm(go)*tanhfast(cn);
      cval = cn; hval = hn;
      if (lane < 12) y1[t*24 + d*12 + lane] = hn;
    }
  }
  __syncthreads();

  // ---- qkv projection: q fp32; K/V interleaved bf16 32B rows -------------
  // kvh row (16 bf16): k0..k5, v0..v5, pad x4
  #pragma unroll
  for (int r = 0; r < 18; ++r){
    int idx = tid + r*256;
    int gq = idx % 72; int t = idx / 72;
    int p = t*88 + n;
    const float* xr = y1 + t*24;
    const float* wr = sqkv + gq*25;
    float a0=0.f, a1=0.f;
    #pragma unroll
    for (int c=0; c<24; c+=2){ a0 += xr[c]*wr[c]; a1 += xr[c+1]*wr[c+1]; }
    float acc = qkv_b[gq] + a0 + a1;
    int s = gq/24, rem = gq - s*24;
    if (s==0) q[p*24+rem] = acc*0.4082482904638631f;   // 1/sqrt(HD)
    else {
      int hh = rem/6, pos = rem - hh*6;
      int off = (s==1) ? pos : (6+pos);
      kvh[((size_t)hh*NPIX + p)*16 + off] = __float2bfloat16(acc);
    }
  }
}

// ============ D3/D4: attention + proj + tail, one block per pixel ==========
__global__ __launch_bounds__(256) void k_attn_fused(
    const float* __restrict__ q, const bf16* __restrict__ kvh,
    const float* __restrict__ rpb,
    const float* __restrict__ pw, const float* __restrict__ pb,
    const float* __restrict__ qkv_w, const float* __restrict__ qkv_b,
    float* __restrict__ q2, bf16* __restrict__ kvh2,
    const float* __restrict__ ow, const float* __restrict__ ob,
    float* __restrict__ out, int last){
  int p = blockIdx.x; int tid = threadIdx.x;
  int h = tid >> 6; int lane = tid & 63;
  int i = p / 88, j = p - i*88;
  int si = min(max(i-12,0),39), sj = min(max(j-12,0),63);
  __shared__ float aorow[24];
  __shared__ float xrow[24];

  float qv[6];
  #pragma unroll
  for (int d=0; d<6; ++d) qv[d] = q[p*24 + h*6 + d];
  const uint4* kv4 = (const uint4*)(kvh + (size_t)h*NPIX*16);
  const uint2* kv2 = (const uint2*)(kvh + (size_t)h*NPIX*16);
  float lgv[10];
  unsigned uv[10][3];           // packed V (6 bf16) kept in registers
  float lmax = -1e30f;
  #pragma unroll
  for (int it=0; it<10; ++it){
    int nb = lane + it*64;
    bool valid = nb < 625;
    int nbc = valid ? nb : 624;
    int a = nbc/25, cc = nbc - a*25;
    int gi = si + a, gj = sj + cc;
    int row = gi*88+gj;
    uint4 r0 = kv4[row*2];      // k0..k5, v0, v1
    uint2 r1 = kv2[row*4+2];    // v2..v5
    float lg = qv[0]*blo(r0.x)+qv[1]*bhi(r0.x)+qv[2]*blo(r0.y)
             + qv[3]*bhi(r0.y)+qv[4]*blo(r0.z)+qv[5]*bhi(r0.z);
    lg += rpb[(h*49 + (gi - i + 24))*49 + (gj - j + 24)];
    lg = valid ? lg : -1e30f;
    lgv[it] = lg;
    uv[it][0] = r0.w; uv[it][1] = r1.x; uv[it][2] = r1.y;
    lmax = fmaxf(lmax, lg);
  }
  #pragma unroll
  for (int off=32; off; off>>=1) lmax = fmaxf(lmax, __shfl_xor(lmax, off));
  float lsum = 0.f;
  #pragma unroll
  for (int it=0; it<10; ++it){
    float pe = __expf(lgv[it]-lmax);
    lgv[it] = pe; lsum += pe;
  }
  #pragma unroll
  for (int off=32; off; off>>=1) lsum += __shfl_xor(lsum, off);
  float acc[6] = {0,0,0,0,0,0};
  #pragma unroll
  for (int it=0; it<10; ++it){
    float pe = lgv[it];
    acc[0] += pe*blo(uv[it][0]); acc[1] += pe*bhi(uv[it][0]);
    acc[2] += pe*blo(uv[it][1]); acc[3] += pe*bhi(uv[it][1]);
    acc[4] += pe*blo(uv[it][2]); acc[5] += pe*bhi(uv[it][2]);
  }
  #pragma unroll
  for (int d=0; d<6; ++d){
    #pragma unroll
    for (int off=32; off; off>>=1) acc[d] += __shfl_xor(acc[d], off);
  }
  if (lane == 0){
    float inv = 1.f/lsum;
    #pragma unroll
    for (int d=0; d<6; ++d) aorow[h*6+d] = acc[d]*inv;
  }
  __syncthreads();

  if (tid < 24){
    float a2 = pb[tid];
    const float* wr = pw + tid*24;
    #pragma unroll
    for (int c=0;c<24;++c) a2 += aorow[c]*wr[c];
    xrow[tid] = a2;
  }
  __syncthreads();

  if (!last){
    if (tid < 72){
      float a2 = qkv_b[tid];
      const float* wr = qkv_w + tid*24;
      #pragma unroll
      for (int c=0;c<24;++c) a2 += xrow[c]*wr[c];
      int s = tid/24, rem = tid - s*24;
      if (s==0) q2[p*24+rem] = a2*0.4082482904638631f;
      else {
        int hh = rem/6, pos = rem - hh*6;
        int off = (s==1) ? pos : (6+pos);
        kvh2[((size_t)hh*NPIX + p)*16 + off] = __float2bfloat16(a2);
      }
    }
  } else {
    if (tid < 5){
      float a2 = ob[tid];
      const float* wr = ow + tid*24;
      #pragma unroll
      for (int c=0;c<24;++c) a2 += xrow[c]*wr[c];
      out[p*5+tid] = a2;
    }
  }
}

extern "C" void kernel_launch(void* const* d_in, const int* in_sizes, int n_in,
                              void* d_out, int out_size, void* d_ws, size_t ws_size,
                              hipStream_t stream) {
  const float* feat    = (const float*)d_in[0];
  const int*   cond    = (const int*)  d_in[1];
  const float* mask    = (const float*)d_in[2];
  const float* emb     = (const float*)d_in[3];
  const float* w_ih_l0 = (const float*)d_in[4];
  const float* w_hh_l0 = (const float*)d_in[5];
  const float* b_ih_l0 = (const float*)d_in[6];
  const float* b_hh_l0 = (const float*)d_in[7];
  const float* w_ih_l1 = (const float*)d_in[8];
  const float* w_hh_l1 = (const float*)d_in[9];
  const float* b_ih_l1 = (const float*)d_in[10];
  const float* b_hh_l1 = (const float*)d_in[11];
  const float* qkv_w   = (const float*)d_in[12];
  const float* qkv_b   = (const float*)d_in[13];
  const float* rpb     = (const float*)d_in[14];
  const float* proj_w  = (const float*)d_in[15];
  const float* proj_b  = (const float*)d_in[16];
  const float* out_w   = (const float*)d_in[17];
  const float* out_b   = (const float*)d_in[18];
  float* out = (float*)d_out;

  float* ws  = (float*)d_ws;
  float* GP  = ws;               // 540672 floats
  float* Q1  = GP  + 540672;     // 135168
  float* Q2  = Q1  + 135168;     // 135168
  bf16*  KV1 = (bf16*)(Q2 + 135168);  // 4*5632*16 bf16 = 360448 halves
  bf16*  KV2 = KV1 + 360448;          // (KV1 byte offset 16B-aligned)

  k_gates0<<<NSEQ*8, 256, 0, stream>>>(feat, cond, mask, emb,
      w_ih_l0, b_ih_l0, b_hh_l0, GP);

  k_core<<<NSEQ, 256, 0, stream>>>(GP, w_hh_l0,
      w_ih_l1, b_ih_l1, b_hh_l1, w_hh_l1, qkv_w, qkv_b, Q1, KV1);

  k_attn_fused<<<NPIX, 256, 0, stream>>>(
      Q1, KV1, rpb, proj_w, proj_b, qkv_w, qkv_b,
      Q2, KV2, out_w, out_b, out, 0);

  k_attn_fused<<<NPIX, 256, 0, stream>>>(
      Q2, KV2, rpb, proj_w, proj_b, qkv_w, qkv_b,
      Q1, KV1, out_w, out_b, out, 1);
}

// Round 9
// 213.985 us; speedup vs baseline: 1.1411x; 1.1411x over previous
//
#include <hip/hip_runtime.h>
#include <hip/hip_bf16.h>

// B=1 T=64 W=88 HP=48 F0=53 HL=12 GATES=48 NU=24 NH=4 HD=6 K=25
// All float tensors are float32; condition is int32.
#define NPIX (64*88)          // 5632
#define NSEQ 88
#define TT 64
#define F0 53
#define GATES 48

typedef __hip_bfloat16 bf16;

__device__ __forceinline__ float frcp(float x){ return __builtin_amdgcn_rcpf(x); }

// unpack first 6 bf16 of a 16B row (uint4) to fp32
__device__ __forceinline__ void unpack6(uint4 r, float* f){
  f[0] = __uint_as_float(r.x << 16);
  f[1] = __uint_as_float(r.x & 0xffff0000u);
  f[2] = __uint_as_float(r.y << 16);
  f[3] = __uint_as_float(r.y & 0xffff0000u);
  f[4] = __uint_as_float(r.z << 16);
  f[5] = __uint_as_float(r.z & 0xffff0000u);
}

// ============ D1: whole LSTM stack + qkv. 88 blocks, everything in LDS =====
// LDS phases (59 KB total):
//  A: sx(3392)+sw0(5088) staging + gates0 -> gbuf(6144)
//  B: rec0 (waves0-1) -> y0 ; waves2-3 stage w1(2400)+sqkv(1800) over sx/sw0
//  C: gates1 -> gbuf ; D: rec1 -> y1 ; E: qkv epilogue
__global__ __launch_bounds__(256) void k_core(
    const float* __restrict__ feat, const int* __restrict__ cond,
    const float* __restrict__ mask, const float* __restrict__ emb,
    const float* __restrict__ wih0, const float* __restrict__ whh0,
    const float* __restrict__ bih0, const float* __restrict__ bhh0,
    const float* __restrict__ wih1, const float* __restrict__ whh1,
    const float* __restrict__ bih1, const float* __restrict__ bhh1,
    const float* __restrict__ qkv_w, const float* __restrict__ qkv_b,
    float* __restrict__ q, bf16* __restrict__ kh, bf16* __restrict__ vh){
  int n = blockIdx.x; int tid = threadIdx.x;
  int wave = tid >> 6; int lane = tid & 63;
  __shared__ float smem[14816];
  float* gbuf = smem;               // 6144 floats, whole lifetime
  float* sx   = smem + 6144;        // 3392  (phase A)
  float* sw0  = smem + 6144+3392;   // 5088  (phase A)
  float* w1   = smem + 6144;        // 2400  (phase B+) aliases sx
  float* sqkv = smem + 6144+2400;   // 1800  (phase B+)
  float* y0   = smem + 6144+4200;   // 1536
  float* y1   = smem + 6144+5736;   // 1536
  float* bsum = smem + 14624;       // 192

  // ---- Phase A: stage x-tile, wih0, bias sums ----
  for (int idx = tid; idx < 2*GATES*F0; idx += 256) sw0[idx] = wih0[idx];
  for (int idx = tid; idx < TT*F0; idx += 256){
    int t = idx / F0, f = idx - t*F0;
    float v;
    if (f < 48)      v = feat[(t*48 + f)*88 + n];
    else if (f < 52) v = emb[cond[t*88+n]*4 + (f-48)];
    else             v = mask[t*88+n];
    sx[idx] = v;
  }
  if (tid < 96)       bsum[tid] = bih0[tid] + bhh0[tid];
  else if (tid < 192) bsum[tid] = bih1[tid-96] + bhh1[tid-96];
  __syncthreads();

  // ---- gates layer 0 (53-MAC dots), 24 rows/thread, all LDS operands ----
  for (int r = 0; r < 24; ++r){
    int row = tid + r*256;
    int d = row / 3072; int rem = row - d*3072;
    int t = rem / 48; int j = rem - t*48;
    const float* xr = sx + t*F0;
    const float* wr = sw0 + (d*GATES + j)*F0;
    float a0=0.f, a1=0.f, a2=0.f, a3=0.f;
    #pragma unroll
    for (int f=0; f<52; f+=4){
      a0 += xr[f  ]*wr[f  ];
      a1 += xr[f+1]*wr[f+1];
      a2 += xr[f+2]*wr[f+2];
      a3 += xr[f+3]*wr[f+3];
    }
    gbuf[(d*TT + t)*GATES + j] = bsum[d*GATES+j] + xr[52]*wr[52] + ((a0+a1)+(a2+a3));
  }
  __syncthreads();

  // ---- Phase B: rec0 (waves 0,1); waves 2,3 stage w1 + sqkv -------------
  if (wave >= 2){
    for (int idx = tid-128; idx < 2*GATES*24; idx += 128){
      int row = idx / 24, f = idx - row*24;
      w1[row*25 + f] = wih1[idx];
    }
    for (int idx = tid-128; idx < 72*24; idx += 128){
      int row = idx / 24, f = idx - row*24;
      sqkv[row*25 + f] = qkv_w[idx];
    }
  } else {
    int d = wave;
    int j = (lane < GATES) ? lane : (lane - GATES);
    int u = j % 12; int grp = j / 12;          // 0:i 1:f 2:g 3:o
    float w[12];
    const float* wb = whh0 + (d*GATES + j)*12;
    #pragma unroll
    for (int m=0;m<12;++m) w[m] = wb[m];
    float negs  = (grp==2) ? -2.f : -1.f;      // tanh(x)=2*sigm(2x)-1
    float amul  = (grp==2) ?  2.f :  1.f;
    float aadd  = (grp==2) ? -1.f :  0.f;
    const float* gb = gbuf + d*TT*GATES + j;
    float hval = 0.f, cval = 0.f;
    int t0 = d ? (TT-1) : 0;
    float gnext = gb[t0*GATES];
    for (int s=0;s<TT;++s){
      int t = d ? (TT-1-s) : s;
      float gg = gnext;
      int tn = d ? max(TT-2-s,0) : min(s+1,TT-1);
      gnext = gb[tn*GATES];                     // prefetch next step
      float h0=__shfl(hval,0), h1=__shfl(hval,1), h2=__shfl(hval,2);
      float h3=__shfl(hval,3), h4=__shfl(hval,4), h5=__shfl(hval,5);
      float h6=__shfl(hval,6), h7=__shfl(hval,7), h8=__shfl(hval,8);
      float h9=__shfl(hval,9), h10=__shfl(hval,10), h11=__shfl(hval,11);
      float a0 = gg + h0*w[0] + h4*w[4] + h8*w[8];
      float a1 = h1*w[1] + h5*w[5] + h9*w[9];
      float a2 = h2*w[2] + h6*w[6] + h10*w[10];
      float a3 = h3*w[3] + h7*w[7] + h11*w[11];
      float dot = (a0+a1)+(a2+a3);
      float act = amul*frcp(1.f + __expf(negs*dot)) + aadd;  // per-lane nonlinearity
      float ai = __shfl(act, u);
      float af = __shfl(act, u+12);
      float ag = __shfl(act, u+24);
      float ao = __shfl(act, u+36);
      float cn = af*cval + ai*ag;
      float th = 2.f*frcp(1.f + __expf(-2.f*cn)) - 1.f;
      hval = ao*th; cval = cn;
      if (lane < 12) y0[t*24 + d*12 + lane] = hval;
    }
  }
  __syncthreads();

  // ---- gates layer 1 (24-MAC dots), overwrites gbuf ----------------------
  for (int r = 0; r < 24; ++r){
    int row = tid + r*256;
    int d = row / 3072; int rem = row - d*3072;
    int t = rem / 48; int j = rem - t*48;
    const float* xr = y0 + t*24;
    const float* wr = w1 + (d*GATES + j)*25;
    float a0=0.f, a1=0.f;
    #pragma unroll
    for (int c=0; c<24; c+=2){ a0 += xr[c]*wr[c]; a1 += xr[c+1]*wr[c+1]; }
    gbuf[(d*TT + t)*GATES + j] = bsum[96 + d*GATES+j] + a0 + a1;
  }
  __syncthreads();

  // ---- rec1 (waves 0,1) --------------------------------------------------
  if (wave < 2){
    int d = wave;
    int j = (lane < GATES) ? lane : (lane - GATES);
    int u = j % 12; int grp = j / 12;
    float w[12];
    const float* wb = whh1 + (d*GATES + j)*12;
    #pragma unroll
    for (int m=0;m<12;++m) w[m] = wb[m];
    float negs  = (grp==2) ? -2.f : -1.f;
    float amul  = (grp==2) ?  2.f :  1.f;
    float aadd  = (grp==2) ? -1.f :  0.f;
    const float* gb = gbuf + d*TT*GATES + j;
    float hval = 0.f, cval = 0.f;
    int t0 = d ? (TT-1) : 0;
    float gnext = gb[t0*GATES];
    for (int s=0;s<TT;++s){
      int t = d ? (TT-1-s) : s;
      float gg = gnext;
      int tn = d ? max(TT-2-s,0) : min(s+1,TT-1);
      gnext = gb[tn*GATES];
      float h0=__shfl(hval,0), h1=__shfl(hval,1), h2=__shfl(hval,2);
      float h3=__shfl(hval,3), h4=__shfl(hval,4), h5=__shfl(hval,5);
      float h6=__shfl(hval,6), h7=__shfl(hval,7), h8=__shfl(hval,8);
      float h9=__shfl(hval,9), h10=__shfl(hval,10), h11=__shfl(hval,11);
      float a0 = gg + h0*w[0] + h4*w[4] + h8*w[8];
      float a1 = h1*w[1] + h5*w[5] + h9*w[9];
      float a2 = h2*w[2] + h6*w[6] + h10*w[10];
      float a3 = h3*w[3] + h7*w[7] + h11*w[11];
      float dot = (a0+a1)+(a2+a3);
      float act = amul*frcp(1.f + __expf(negs*dot)) + aadd;
      float ai = __shfl(act, u);
      float af = __shfl(act, u+12);
      float ag = __shfl(act, u+24);
      float ao = __shfl(act, u+36);
      float cn = af*cval + ai*ag;
      float th = 2.f*frcp(1.f + __expf(-2.f*cn)) - 1.f;
      hval = ao*th; cval = cn;
      if (lane < 12) y1[t*24 + d*12 + lane] = hval;
    }
  }
  __syncthreads();

  // ---- qkv projection: q fp32, K/V bf16 rows of 8 (16 B) -----------------
  for (int r = 0; r < 18; ++r){
    int idx = tid + r*256;
    int gq = idx % 72; int t = idx / 72;
    int p = t*88 + n;
    const float* xr = y1 + t*24;
    const float* wr = sqkv + gq*25;
    float a0=0.f, a1=0.f;
    #pragma unroll
    for (int c=0; c<24; c+=2){ a0 += xr[c]*wr[c]; a1 += xr[c+1]*wr[c+1]; }
    float acc = qkv_b[gq] + a0 + a1;
    int s = gq/24, rem = gq - s*24;
    if (s==0) q[p*24+rem] = acc*0.4082482904638631f;   // 1/sqrt(HD)
    else {
      int hh = rem/6, pos = rem - hh*6;
      bf16* dst = (s==1) ? kh : vh;
      dst[((size_t)hh*NPIX + p)*8 + pos] = __float2bfloat16(acc);
    }
  }
}

// ============ D2/D3: attention + proj + tail (R7 structure) ===============
__global__ __launch_bounds__(256) void k_attn_fused(
    const float* __restrict__ q, const bf16* __restrict__ kh,
    const bf16* __restrict__ vh, const float* __restrict__ rpb,
    const float* __restrict__ pw, const float* __restrict__ pb,
    const float* __restrict__ qkv_w, const float* __restrict__ qkv_b,
    float* __restrict__ q2, bf16* __restrict__ kh2, bf16* __restrict__ vh2,
    const float* __restrict__ ow, const float* __restrict__ ob,
    float* __restrict__ out, int last){
  int p = blockIdx.x; int tid = threadIdx.x;
  int h = tid >> 6; int lane = tid & 63;
  int i = p / 88, j = p - i*88;
  int si = min(max(i-12,0),39), sj = min(max(j-12,0),63);
  __shared__ float aorow[24];
  __shared__ float xrow[24];

  float qv[6];
  #pragma unroll
  for (int d=0; d<6; ++d) qv[d] = q[p*24 + h*6 + d];
  const uint4* kb = (const uint4*)(kh + (size_t)h*NPIX*8);
  const uint4* vb = (const uint4*)(vh + (size_t)h*NPIX*8);
  float lgv[10]; int roff[10];
  float lmax = -1e30f;
  #pragma unroll
  for (int it=0; it<10; ++it){
    int nb = lane + it*64;
    bool valid = nb < 625;
    int nbc = valid ? nb : 624;
    int a = nbc/25, cc = nbc - a*25;
    int gi = si + a, gj = sj + cc;
    int row = gi*88+gj;
    roff[it] = row;
    float kr[6];
    unpack6(kb[row], kr);
    float lg = qv[0]*kr[0]+qv[1]*kr[1]+qv[2]*kr[2]+qv[3]*kr[3]+qv[4]*kr[4]+qv[5]*kr[5];
    lg += rpb[(h*49 + (gi - i + 24))*49 + (gj - j + 24)];
    lg = valid ? lg : -1e30f;
    lgv[it] = lg;
    lmax = fmaxf(lmax, lg);
  }
  #pragma unroll
  for (int off=32; off; off>>=1) lmax = fmaxf(lmax, __shfl_xor(lmax, off));
  float lsum = 0.f;
  #pragma unroll
  for (int it=0; it<10; ++it){
    float pe = __expf(lgv[it]-lmax);
    lgv[it] = pe; lsum += pe;
  }
  #pragma unroll
  for (int off=32; off; off>>=1) lsum += __shfl_xor(lsum, off);
  float acc[6] = {0,0,0,0,0,0};
  #pragma unroll
  for (int it=0; it<10; ++it){
    float vr[6];
    unpack6(vb[roff[it]], vr);
    float pe = lgv[it];
    #pragma unroll
    for (int d=0; d<6; ++d) acc[d] += pe*vr[d];
  }
  #pragma unroll
  for (int d=0; d<6; ++d){
    #pragma unroll
    for (int off=32; off; off>>=1) acc[d] += __shfl_xor(acc[d], off);
  }
  if (lane == 0){
    float inv = 1.f/lsum;
    #pragma unroll
    for (int d=0; d<6; ++d) aorow[h*6+d] = acc[d]*inv;
  }
  __syncthreads();

  if (tid < 24){
    float a2 = pb[tid];
    const float* wr = pw + tid*24;
    #pragma unroll
    for (int c=0;c<24;++c) a2 += aorow[c]*wr[c];
    xrow[tid] = a2;
  }
  __syncthreads();

  if (!last){
    if (tid < 72){
      float a2 = qkv_b[tid];
      const float* wr = qkv_w + tid*24;
      #pragma unroll
      for (int c=0;c<24;++c) a2 += xrow[c]*wr[c];
      int s = tid/24, rem = tid - s*24;
      if (s==0) q2[p*24+rem] = a2*0.4082482904638631f;
      else {
        int hh = rem/6, pos = rem - hh*6;
        bf16* dst = (s==1) ? kh2 : vh2;
        dst[((size_t)hh*NPIX + p)*8 + pos] = __float2bfloat16(a2);
      }
    }
  } else {
    if (tid < 5){
      float a2 = ob[tid];
      const float* wr = ow + tid*24;
      #pragma unroll
      for (int c=0;c<24;++c) a2 += xrow[c]*wr[c];
      out[p*5+tid] = a2;
    }
  }
}

extern "C" void kernel_launch(void* const* d_in, const int* in_sizes, int n_in,
                              void* d_out, int out_size, void* d_ws, size_t ws_size,
                              hipStream_t stream) {
  const float* feat    = (const float*)d_in[0];
  const int*   cond    = (const int*)  d_in[1];
  const float* mask    = (const float*)d_in[2];
  const float* emb     = (const float*)d_in[3];
  const float* w_ih_l0 = (const float*)d_in[4];
  const float* w_hh_l0 = (const float*)d_in[5];
  const float* b_ih_l0 = (const float*)d_in[6];
  const float* b_hh_l0 = (const float*)d_in[7];
  const float* w_ih_l1 = (const float*)d_in[8];
  const float* w_hh_l1 = (const float*)d_in[9];
  const float* b_ih_l1 = (const float*)d_in[10];
  const float* b_hh_l1 = (const float*)d_in[11];
  const float* qkv_w   = (const float*)d_in[12];
  const float* qkv_b   = (const float*)d_in[13];
  const float* rpb     = (const float*)d_in[14];
  const float* proj_w  = (const float*)d_in[15];
  const float* proj_b  = (const float*)d_in[16];
  const float* out_w   = (const float*)d_in[17];
  const float* out_b   = (const float*)d_in[18];
  float* out = (float*)d_out;

  float* ws  = (float*)d_ws;
  float* Q1  = ws;                    // 135168 floats
  float* Q2  = Q1 + 135168;           // 135168
  bf16*  KH1 = (bf16*)(Q2 + 135168);  // 4*5632*8 = 180224 halves each
  bf16*  VH1 = KH1 + 180224;
  bf16*  KH2 = VH1 + 180224;
  bf16*  VH2 = KH2 + 180224;

  k_core<<<NSEQ, 256, 0, stream>>>(
      feat, cond, mask, emb,
      w_ih_l0, w_hh_l0, b_ih_l0, b_hh_l0,
      w_ih_l1, w_hh_l1, b_ih_l1, b_hh_l1,
      qkv_w, qkv_b, Q1, KH1, VH1);

  k_attn_fused<<<NPIX, 256, 0, stream>>>(
      Q1, KH1, VH1, rpb, proj_w, proj_b, qkv_w, qkv_b,
      Q2, KH2, VH2, out_w, out_b, out, 0);

  k_attn_fused<<<NPIX, 256, 0, stream>>>(
      Q2, KH2, VH2, rpb, proj_w, proj_b, qkv_w, qkv_b,
      Q1, KH1, VH1, out_w, out_b, out, 1);
}

// Round 10
// 210.318 us; speedup vs baseline: 1.1610x; 1.0174x over previous
//
#include <hip/hip_runtime.h>
#include <hip/hip_bf16.h>

// B=1 T=64 W=88 HP=48 F0=53 HL=12 GATES=48 NU=24 NH=4 HD=6 K=25
// All float tensors are float32; condition is int32.
#define NPIX (64*88)          // 5632
#define NSEQ 88
#define TT 64
#define F0 53
#define GATES 48

typedef __hip_bfloat16 bf16;

__device__ __forceinline__ float frcp(float x){ return __builtin_amdgcn_rcpf(x); }

// unpack first 6 bf16 of a 16B row (uint4) to fp32
__device__ __forceinline__ void unpack6(uint4 r, float* f){
  f[0] = __uint_as_float(r.x << 16);
  f[1] = __uint_as_float(r.x & 0xffff0000u);
  f[2] = __uint_as_float(r.y << 16);
  f[3] = __uint_as_float(r.y & 0xffff0000u);
  f[4] = __uint_as_float(r.z << 16);
  f[5] = __uint_as_float(r.z & 0xffff0000u);
}

// ============ D1: whole LSTM stack + qkv. 88 blocks x 1024 threads =========
__global__ __launch_bounds__(1024) void k_core(
    const float* __restrict__ feat, const int* __restrict__ cond,
    const float* __restrict__ mask, const float* __restrict__ emb,
    const float* __restrict__ wih0, const float* __restrict__ whh0,
    const float* __restrict__ bih0, const float* __restrict__ bhh0,
    const float* __restrict__ wih1, const float* __restrict__ whh1,
    const float* __restrict__ bih1, const float* __restrict__ bhh1,
    const float* __restrict__ qkv_w, const float* __restrict__ qkv_b,
    float* __restrict__ q, bf16* __restrict__ kh, bf16* __restrict__ vh){
  int n = blockIdx.x; int tid = threadIdx.x;
  int wave = tid >> 6; int lane = tid & 63;
  __shared__ float smem[14816];
  float* gbuf = smem;               // 6144 floats, whole lifetime
  float* sx   = smem + 6144;        // 3392  (phase A)
  float* sw0  = smem + 6144+3392;   // 5088  (phase A)
  float* w1   = smem + 6144;        // 2400  (phase B+) aliases sx
  float* sqkv = smem + 6144+2400;   // 1800  (phase B+)
  float* y0   = smem + 6144+4200;   // 1536
  float* y1   = smem + 6144+5736;   // 1536
  float* bsum = smem + 14624;       // 192

  // ---- Phase A: stage x-tile, wih0, bias sums ----
  for (int idx = tid; idx < 2*GATES*F0; idx += 1024) sw0[idx] = wih0[idx];
  for (int idx = tid; idx < TT*F0; idx += 1024){
    int t = idx / F0, f = idx - t*F0;
    float v;
    if (f < 48)      v = feat[(t*48 + f)*88 + n];
    else if (f < 52) v = emb[cond[t*88+n]*4 + (f-48)];
    else             v = mask[t*88+n];
    sx[idx] = v;
  }
  if (tid < 96)       bsum[tid] = bih0[tid] + bhh0[tid];
  else if (tid < 192) bsum[tid] = bih1[tid-96] + bhh1[tid-96];
  __syncthreads();

  // ---- gates layer 0 (53-MAC dots), 6 rows/thread, all LDS operands ----
  #pragma unroll
  for (int r = 0; r < 6; ++r){
    int row = tid + r*1024;
    int d = row / 3072; int rem = row - d*3072;
    int t = rem / 48; int j = rem - t*48;
    const float* xr = sx + t*F0;
    const float* wr = sw0 + (d*GATES + j)*F0;
    float a0=0.f, a1=0.f, a2=0.f, a3=0.f;
    #pragma unroll
    for (int f=0; f<52; f+=4){
      a0 += xr[f  ]*wr[f  ];
      a1 += xr[f+1]*wr[f+1];
      a2 += xr[f+2]*wr[f+2];
      a3 += xr[f+3]*wr[f+3];
    }
    gbuf[(d*TT + t)*GATES + j] = bsum[d*GATES+j] + xr[52]*wr[52] + ((a0+a1)+(a2+a3));
  }
  __syncthreads();

  // ---- Phase B: rec0 (waves 0,1); waves >=2 stage w1 + sqkv -------------
  if (wave >= 2){
    for (int idx = tid-128; idx < 2*GATES*24; idx += 896){
      int row = idx / 24, f = idx - row*24;
      w1[row*25 + f] = wih1[idx];
    }
    for (int idx = tid-128; idx < 72*24; idx += 896){
      int row = idx / 24, f = idx - row*24;
      sqkv[row*25 + f] = qkv_w[idx];
    }
  } else {
    int d = wave;
    int j = (lane < GATES) ? lane : (lane - GATES);
    int u = j % 12; int grp = j / 12;          // 0:i 1:f 2:g 3:o
    float w[12];
    const float* wb = whh0 + (d*GATES + j)*12;
    #pragma unroll
    for (int m=0;m<12;++m) w[m] = wb[m];
    float negs  = (grp==2) ? -2.f : -1.f;      // tanh(x)=2*sigm(2x)-1
    float amul  = (grp==2) ?  2.f :  1.f;
    float aadd  = (grp==2) ? -1.f :  0.f;
    const float* gb = gbuf + d*TT*GATES + j;
    float hval = 0.f, cval = 0.f;
    int t0 = d ? (TT-1) : 0;
    float gnext = gb[t0*GATES];
    for (int s=0;s<TT;++s){
      int t = d ? (TT-1-s) : s;
      float gg = gnext;
      int tn = d ? max(TT-2-s,0) : min(s+1,TT-1);
      gnext = gb[tn*GATES];                     // prefetch next step
      float h0=__shfl(hval,0), h1=__shfl(hval,1), h2=__shfl(hval,2);
      float h3=__shfl(hval,3), h4=__shfl(hval,4), h5=__shfl(hval,5);
      float h6=__shfl(hval,6), h7=__shfl(hval,7), h8=__shfl(hval,8);
      float h9=__shfl(hval,9), h10=__shfl(hval,10), h11=__shfl(hval,11);
      float a0 = gg + h0*w[0] + h4*w[4] + h8*w[8];
      float a1 = h1*w[1] + h5*w[5] + h9*w[9];
      float a2 = h2*w[2] + h6*w[6] + h10*w[10];
      float a3 = h3*w[3] + h7*w[7] + h11*w[11];
      float dot = (a0+a1)+(a2+a3);
      float act = amul*frcp(1.f + __expf(negs*dot)) + aadd;  // per-lane nonlinearity
      float ai = __shfl(act, u);
      float af = __shfl(act, u+12);
      float ag = __shfl(act, u+24);
      float ao = __shfl(act, u+36);
      float cn = af*cval + ai*ag;
      float th = 2.f*frcp(1.f + __expf(-2.f*cn)) - 1.f;
      hval = ao*th; cval = cn;
      if (lane < 12) y0[t*24 + d*12 + lane] = hval;
    }
  }
  __syncthreads();

  // ---- gates layer 1 (24-MAC dots), overwrites gbuf ----------------------
  #pragma unroll
  for (int r = 0; r < 6; ++r){
    int row = tid + r*1024;
    int d = row / 3072; int rem = row - d*3072;
    int t = rem / 48; int j = rem - t*48;
    const float* xr = y0 + t*24;
    const float* wr = w1 + (d*GATES + j)*25;
    float a0=0.f, a1=0.f;
    #pragma unroll
    for (int c=0; c<24; c+=2){ a0 += xr[c]*wr[c]; a1 += xr[c+1]*wr[c+1]; }
    gbuf[(d*TT + t)*GATES + j] = bsum[96 + d*GATES+j] + a0 + a1;
  }
  __syncthreads();

  // ---- rec1 (waves 0,1) --------------------------------------------------
  if (wave < 2){
    int d = wave;
    int j = (lane < GATES) ? lane : (lane - GATES);
    int u = j % 12; int grp = j / 12;
    float w[12];
    const float* wb = whh1 + (d*GATES + j)*12;
    #pragma unroll
    for (int m=0;m<12;++m) w[m] = wb[m];
    float negs  = (grp==2) ? -2.f : -1.f;
    float amul  = (grp==2) ?  2.f :  1.f;
    float aadd  = (grp==2) ? -1.f :  0.f;
    const float* gb = gbuf + d*TT*GATES + j;
    float hval = 0.f, cval = 0.f;
    int t0 = d ? (TT-1) : 0;
    float gnext = gb[t0*GATES];
    for (int s=0;s<TT;++s){
      int t = d ? (TT-1-s) : s;
      float gg = gnext;
      int tn = d ? max(TT-2-s,0) : min(s+1,TT-1);
      gnext = gb[tn*GATES];
      float h0=__shfl(hval,0), h1=__shfl(hval,1), h2=__shfl(hval,2);
      float h3=__shfl(hval,3), h4=__shfl(hval,4), h5=__shfl(hval,5);
      float h6=__shfl(hval,6), h7=__shfl(hval,7), h8=__shfl(hval,8);
      float h9=__shfl(hval,9), h10=__shfl(hval,10), h11=__shfl(hval,11);
      float a0 = gg + h0*w[0] + h4*w[4] + h8*w[8];
      float a1 = h1*w[1] + h5*w[5] + h9*w[9];
      float a2 = h2*w[2] + h6*w[6] + h10*w[10];
      float a3 = h3*w[3] + h7*w[7] + h11*w[11];
      float dot = (a0+a1)+(a2+a3);
      float act = amul*frcp(1.f + __expf(negs*dot)) + aadd;
      float ai = __shfl(act, u);
      float af = __shfl(act, u+12);
      float ag = __shfl(act, u+24);
      float ao = __shfl(act, u+36);
      float cn = af*cval + ai*ag;
      float th = 2.f*frcp(1.f + __expf(-2.f*cn)) - 1.f;
      hval = ao*th; cval = cn;
      if (lane < 12) y1[t*24 + d*12 + lane] = hval;
    }
  }
  __syncthreads();

  // ---- qkv projection: q fp32, K/V bf16 rows of 8 (16 B) -----------------
  for (int idx = tid; idx < TT*72; idx += 1024){
    int gq = idx % 72; int t = idx / 72;
    int p = t*88 + n;
    const float* xr = y1 + t*24;
    const float* wr = sqkv + gq*25;
    float a0=0.f, a1=0.f;
    #pragma unroll
    for (int c=0; c<24; c+=2){ a0 += xr[c]*wr[c]; a1 += xr[c+1]*wr[c+1]; }
    float acc = qkv_b[gq] + a0 + a1;
    int s = gq/24, rem = gq - s*24;
    if (s==0) q[p*24+rem] = acc*0.4082482904638631f;   // 1/sqrt(HD)
    else {
      int hh = rem/6, pos = rem - hh*6;
      bf16* dst = (s==1) ? kh : vh;
      dst[((size_t)hh*NPIX + p)*8 + pos] = __float2bfloat16(acc);
    }
  }
}

// ============ attention: block = (head, 4x2 pixel tile), LDS K/V tile ======
// grid 4*16*44 = 2816 blocks x 512 threads. Tile window 28x26 staged coalesced.
__global__ __launch_bounds__(512) void k_attn(
    const float* __restrict__ q, const bf16* __restrict__ kh,
    const bf16* __restrict__ vh, const float* __restrict__ rpb,
    float* __restrict__ ao){
  int b = blockIdx.x;
  int h = b / 704; int rem = b - h*704;
  int ti = rem / 44, tj = rem - ti*44;
  int i0 = ti*4, j0 = tj*2;
  int tid = threadIdx.x;
  int w = tid >> 6; int lane = tid & 63;
  int osi = min(max(i0-12,0),39);
  int osj = min(max(j0-12,0),63);

  __shared__ uint4 kt[28*26];
  __shared__ uint4 vt[28*26];
  const uint4* kg = (const uint4*)(kh + (size_t)h*NPIX*8);
  const uint4* vg = (const uint4*)(vh + (size_t)h*NPIX*8);
  for (int idx = tid; idx < 28*26; idx += 512){
    int a = idx / 26, cc = idx - a*26;
    int gi = min(osi + a, 63), gj = min(osj + cc, 87);
    int src = gi*88 + gj;
    kt[idx] = kg[src];
    vt[idx] = vg[src];
  }
  __syncthreads();

  int pi = i0 + (w>>1), pj = j0 + (w&1);
  int p = pi*88 + pj;
  int dsi = min(max(pi-12,0),39) - osi;     // 0..3
  int dsj = min(max(pj-12,0),63) - osj;     // 0..1
  int rbi = osi + dsi - pi + 24;
  int rbj = osj + dsj - pj + 24;

  float qv[6];
  #pragma unroll
  for (int d=0; d<6; ++d) qv[d] = q[p*24 + h*6 + d];

  float lgv[10]; int rof[10];
  float lmax = -1e30f;
  #pragma unroll
  for (int it=0; it<10; ++it){
    int nb = lane + it*64;
    bool valid = nb < 625;
    int nbc = valid ? nb : 624;
    int a = nbc/25, cc = nbc - a*25;
    int r = (a+dsi)*26 + (cc+dsj);
    rof[it] = r;
    float kr[6];
    unpack6(kt[r], kr);
    float lg = qv[0]*kr[0]+qv[1]*kr[1]+qv[2]*kr[2]+qv[3]*kr[3]+qv[4]*kr[4]+qv[5]*kr[5];
    lg += rpb[(h*49 + (a + rbi))*49 + (cc + rbj)];
    lg = valid ? lg : -1e30f;
    lgv[it] = lg;
    lmax = fmaxf(lmax, lg);
  }
  #pragma unroll
  for (int off=32; off; off>>=1) lmax = fmaxf(lmax, __shfl_xor(lmax, off));
  float lsum = 0.f;
  #pragma unroll
  for (int it=0; it<10; ++it){
    float pe = __expf(lgv[it]-lmax);      // invalid -> exp(-huge)=0
    lgv[it] = pe; lsum += pe;
  }
  #pragma unroll
  for (int off=32; off; off>>=1) lsum += __shfl_xor(lsum, off);
  float acc[6] = {0,0,0,0,0,0};
  #pragma unroll
  for (int it=0; it<10; ++it){
    float vr[6];
    unpack6(vt[rof[it]], vr);
    float pe = lgv[it];
    #pragma unroll
    for (int d=0; d<6; ++d) acc[d] += pe*vr[d];
  }
  #pragma unroll
  for (int d=0; d<6; ++d){
    #pragma unroll
    for (int off=32; off; off>>=1) acc[d] += __shfl_xor(acc[d], off);
  }
  if (lane == 0){
    float inv = frcp(lsum);
    #pragma unroll
    for (int d=0; d<6; ++d) ao[p*24 + h*6 + d] = acc[d]*inv;
  }
}

// ============ proj + qkv (between NATTEN layers), 1 wave per pixel =========
__global__ __launch_bounds__(64) void k_proj_qkv(const float* __restrict__ ain,
    const float* __restrict__ pw, const float* __restrict__ pb,
    const float* __restrict__ qkv_w, const float* __restrict__ qkv_b,
    float* __restrict__ q2, bf16* __restrict__ kh2, bf16* __restrict__ vh2){
  int p = blockIdx.x; int tid = threadIdx.x;
  __shared__ float arow[24];
  __shared__ float xrow[24];
  if (tid < 24) arow[tid] = ain[p*24+tid];
  __syncthreads();
  if (tid < 24){
    float a2 = pb[tid];
    const float* wr = pw + tid*24;
    #pragma unroll
    for (int c=0;c<24;++c) a2 += arow[c]*wr[c];
    xrow[tid] = a2;
  }
  __syncthreads();
  for (int g = tid; g < 72; g += 64){
    float a2 = qkv_b[g];
    const float* wr = qkv_w + g*24;
    #pragma unroll
    for (int c=0;c<24;++c) a2 += xrow[c]*wr[c];
    int s = g/24, rem = g - s*24;
    if (s==0) q2[p*24+rem] = a2*0.4082482904638631f;
    else {
      int hh = rem/6, pos = rem - hh*6;
      bf16* dst = (s==1) ? kh2 : vh2;
      dst[((size_t)hh*NPIX + p)*8 + pos] = __float2bfloat16(a2);
    }
  }
}

// ============ proj + final 24->5 head ======================================
__global__ __launch_bounds__(64) void k_proj_out(const float* __restrict__ ain,
    const float* __restrict__ pw, const float* __restrict__ pb,
    const float* __restrict__ ow, const float* __restrict__ ob,
    float* __restrict__ out){
  int p = blockIdx.x; int tid = threadIdx.x;
  __shared__ float arow[24];
  __shared__ float xrow[24];
  if (tid < 24) arow[tid] = ain[p*24+tid];
  __syncthreads();
  if (tid < 24){
    float a2 = pb[tid];
    const float* wr = pw + tid*24;
    #pragma unroll
    for (int c=0;c<24;++c) a2 += arow[c]*wr[c];
    xrow[tid] = a2;
  }
  __syncthreads();
  if (tid < 5){
    float a2 = ob[tid];
    const float* wr = ow + tid*24;
    #pragma unroll
    for (int c=0;c<24;++c) a2 += xrow[c]*wr[c];
    out[p*5+tid] = a2;
  }
}

extern "C" void kernel_launch(void* const* d_in, const int* in_sizes, int n_in,
                              void* d_out, int out_size, void* d_ws, size_t ws_size,
                              hipStream_t stream) {
  const float* feat    = (const float*)d_in[0];
  const int*   cond    = (const int*)  d_in[1];
  const float* mask    = (const float*)d_in[2];
  const float* emb     = (const float*)d_in[3];
  const float* w_ih_l0 = (const float*)d_in[4];
  const float* w_hh_l0 = (const float*)d_in[5];
  const float* b_ih_l0 = (const float*)d_in[6];
  const float* b_hh_l0 = (const float*)d_in[7];
  const float* w_ih_l1 = (const float*)d_in[8];
  const float* w_hh_l1 = (const float*)d_in[9];
  const float* b_ih_l1 = (const float*)d_in[10];
  const float* b_hh_l1 = (const float*)d_in[11];
  const float* qkv_w   = (const float*)d_in[12];
  const float* qkv_b   = (const float*)d_in[13];
  const float* rpb     = (const float*)d_in[14];
  const float* proj_w  = (const float*)d_in[15];
  const float* proj_b  = (const float*)d_in[16];
  const float* out_w   = (const float*)d_in[17];
  const float* out_b   = (const float*)d_in[18];
  float* out = (float*)d_out;

  float* ws  = (float*)d_ws;
  float* Q1  = ws;                    // 135168 floats
  float* Q2  = Q1 + 135168;           // 135168
  float* AO  = Q2 + 135168;           // 135168 (reused by both layers)
  bf16*  KH1 = (bf16*)(AO + 135168);  // 4*5632*8 = 180224 halves each
  bf16*  VH1 = KH1 + 180224;
  bf16*  KH2 = VH1 + 180224;
  bf16*  VH2 = KH2 + 180224;

  k_core<<<NSEQ, 1024, 0, stream>>>(
      feat, cond, mask, emb,
      w_ih_l0, w_hh_l0, b_ih_l0, b_hh_l0,
      w_ih_l1, w_hh_l1, b_ih_l1, b_hh_l1,
      qkv_w, qkv_b, Q1, KH1, VH1);

  k_attn<<<4*16*44, 512, 0, stream>>>(Q1, KH1, VH1, rpb, AO);

  k_proj_qkv<<<NPIX, 64, 0, stream>>>(AO, proj_w, proj_b, qkv_w, qkv_b,
                                      Q2, KH2, VH2);

  k_attn<<<4*16*44, 512, 0, stream>>>(Q2, KH2, VH2, rpb, AO);

  k_proj_out<<<NPIX, 64, 0, stream>>>(AO, proj_w, proj_b, out_w, out_b, out);
}